// Round 6
// baseline (119.805 us; speedup 1.0000x reference)
//
#include <hip/hip_runtime.h>
#include <hip/hip_bf16.h>
#include <cstdint>

#define NHEADS 8
#define NPOINTS 4

typedef __bf16 bf16x8 __attribute__((ext_vector_type(8)));
typedef float f32x4 __attribute__((ext_vector_type(4)));

#define AS1 __attribute__((address_space(1)))
#define AS3 __attribute__((address_space(3)))

__device__ __forceinline__ ushort f2bf_rn(float x) {
  union { float f; uint32_t u; } c; c.f = x;
  uint32_t r = c.u + 0x7fffu + ((c.u >> 16) & 1u);
  return (ushort)(r >> 16);
}
__device__ __forceinline__ float bf2f(ushort h) {
  union { uint32_t u; float f; } c; c.u = ((uint32_t)h) << 16; return c.f;
}
__device__ __forceinline__ uint pack2(ushort a, ushort b) {
  return (uint)a | ((uint)b << 16);
}

// LDS rows are 128 B = 8 granules of 16 B: granules 0-3 = hi (32 bf16),
// granules 4-7 = lo. Granule index XOR-swizzled by (row&7) (G4 pattern;
// conflict-free reads verified: SQ_LDS_BANK_CONFLICT ~0 rounds 3-5).
__device__ __forceinline__ int gidx(int row, int g0) {
  return row * 64 + ((g0 ^ (row & 7)) << 3);
}

// Convert one thread's A chunk (fp32 -> hi/lo bf16) and store to LDS buffer.
template<int TM>
__device__ __forceinline__ void a_convert_store(
    ushort* Ab, int arow, int agq, float4 areg0, float4 areg1)
{
  if constexpr (TM == 64) {
    const float v[8] = {areg0.x, areg0.y, areg0.z, areg0.w,
                        areg1.x, areg1.y, areg1.z, areg1.w};
    ushort h[8], l[8];
#pragma unroll
    for (int j = 0; j < 8; ++j) {
      h[j] = f2bf_rn(v[j]);
      l[j] = f2bf_rn(v[j] - bf2f(h[j]));
    }
    uint4 hv = {pack2(h[0],h[1]), pack2(h[2],h[3]), pack2(h[4],h[5]), pack2(h[6],h[7])};
    uint4 lv = {pack2(l[0],l[1]), pack2(l[2],l[3]), pack2(l[4],l[5]), pack2(l[6],l[7])};
    *(uint4*)&Ab[gidx(arow, agq)]     = hv;
    *(uint4*)&Ab[gidx(arow, agq + 4)] = lv;
  } else {
    const float v[4] = {areg0.x, areg0.y, areg0.z, areg0.w};
    ushort h[4], l[4];
#pragma unroll
    for (int j = 0; j < 4; ++j) {
      h[j] = f2bf_rn(v[j]);
      l[j] = f2bf_rn(v[j] - bf2f(h[j]));
    }
    const int g = agq >> 1, half = (agq & 1) * 4;
    uint2 hv = {pack2(h[0],h[1]), pack2(h[2],h[3])};
    uint2 lv = {pack2(l[0],l[1]), pack2(l[2],l[3])};
    *(uint2*)&Ab[gidx(arow, g)     + half] = hv;
    *(uint2*)&Ab[gidx(arow, g + 4) + half] = lv;
  }
}

// ---------------------------------------------------------------------------
// Split-bf16 (3x MFMA) GEMM, N=256: C[M,256] = A[M,K] @ B[K,256] + bias.
// Double-buffered LDS pipeline, ONE barrier per K-step (BK=32):
//   iter t: issue A(t+1)->regs + B(t+1)->global_load_lds into buf^1,
//           MFMA on buf, convert/ds_write A(t+1), __syncthreads().
// The barrier's vmcnt(0) drain lands ~an MFMA-phase after issue -> latency
// hidden (T3-lite). LDS = 2*(TM*128B) + 2*32KB = 80 KB @ TM=64 (2 blk/CU).
// B comes PRE-SWIZZLED from prep_wt (linear LDS dest + pre-swizzled source
// + swizzled read, rule #21).
// ---------------------------------------------------------------------------
template<int TM>
__global__ __launch_bounds__(256, 2) void gemm_split3_n256(
    const float* __restrict__ A,
    const ushort* __restrict__ Bprep,   // [K/32][16384] pre-swizzled ushorts
    const float* __restrict__ bias, float* __restrict__ C,
    int M, int K)
{
  constexpr int MT = TM / 16;
  constexpr int AHALF = TM * 64;        // ushorts per A buffer
  constexpr int BHALF = 16384;          // ushorts per B buffer
  __shared__ ushort smem[2 * AHALF + 2 * BHALF];
  const int tid  = threadIdx.x;
  const int lane = tid & 63, wave = tid >> 6;
  const int wn   = wave * 64;
  const int lrow = lane & 15, lgrp = lane >> 4;
  const long brow = (long)blockIdx.x * TM;
  const int NT = K >> 5;

  f32x4 acc[MT][4] = {};

  int arow, agq;
  if constexpr (TM == 64) { arow = tid >> 2; agq = tid & 3; }
  else                    { arow = tid >> 3; agq = tid & 7; }
  const float* Abase = &A[(size_t)(brow + arow) * K];

  float4 areg0 = {}, areg1 = {};

  // ---- prologue: stage chunk 0 into buffers 0 ----
  if constexpr (TM == 64) {
    areg0 = *(const float4*)(Abase + agq * 8);
    areg1 = *(const float4*)(Abase + agq * 8 + 4);
  } else {
    areg0 = *(const float4*)(Abase + agq * 4);
  }
#pragma unroll
  for (int j = 0; j < 8; ++j) {
    const ushort* src = Bprep + (size_t)wave * 512 + (size_t)j * 2048 + (size_t)lane * 8;
    __builtin_amdgcn_global_load_lds((const AS1 void*)src,
        (AS3 void*)&smem[2 * AHALF + wave * 512 + j * 2048], 16, 0, 0);
  }
  a_convert_store<TM>(smem, arow, agq, areg0, areg1);
  __syncthreads();

  for (int t = 0; t < NT; ++t) {
    const int cur = t & 1;
    ushort* Ab = smem + cur * AHALF;
    ushort* Bb = smem + 2 * AHALF + cur * BHALF;
    ushort* An = smem + (cur ^ 1) * AHALF;
    ushort* Bn = smem + 2 * AHALF + (cur ^ 1) * BHALF;
    const bool more = (t + 1 < NT);

    // ---- issue next chunk's loads (fly under MFMA) ----
    if (more) {
      if constexpr (TM == 64) {
        areg0 = *(const float4*)(Abase + (t + 1) * 32 + agq * 8);
        areg1 = *(const float4*)(Abase + (t + 1) * 32 + agq * 8 + 4);
      } else {
        areg0 = *(const float4*)(Abase + (t + 1) * 32 + agq * 4);
      }
#pragma unroll
      for (int j = 0; j < 8; ++j) {
        const ushort* src = Bprep + (size_t)(t + 1) * BHALF + (size_t)wave * 512
                          + (size_t)j * 2048 + (size_t)lane * 8;
        __builtin_amdgcn_global_load_lds((const AS1 void*)src,
            (AS3 void*)&Bn[wave * 512 + j * 2048], 16, 0, 0);
      }
    }

    // ---- MFMA on current buffers ----
    bf16x8 ah[MT], al[MT];
#pragma unroll
    for (int mt = 0; mt < MT; ++mt) {
      const int r = mt * 16 + lrow;
      ah[mt] = *(const bf16x8*)&Ab[gidx(r, lgrp)];
      al[mt] = *(const bf16x8*)&Ab[gidx(r, lgrp + 4)];
    }
#pragma unroll
    for (int nt = 0; nt < 4; ++nt) {
      const int r = wn + nt * 16 + lrow;
      const bf16x8 bh = *(const bf16x8*)&Bb[gidx(r, lgrp)];
      const bf16x8 bl = *(const bf16x8*)&Bb[gidx(r, lgrp + 4)];
#pragma unroll
      for (int mt = 0; mt < MT; ++mt) {
        acc[mt][nt] = __builtin_amdgcn_mfma_f32_16x16x32_bf16(ah[mt], bh, acc[mt][nt], 0, 0, 0);
        acc[mt][nt] = __builtin_amdgcn_mfma_f32_16x16x32_bf16(ah[mt], bl, acc[mt][nt], 0, 0, 0);
        acc[mt][nt] = __builtin_amdgcn_mfma_f32_16x16x32_bf16(al[mt], bh, acc[mt][nt], 0, 0, 0);
      }
    }

    // ---- convert + write A(t+1) (vmcnt wait on areg lands here) ----
    if (more)
      a_convert_store<TM>(An, arow, agq, areg0, areg1);

    __syncthreads();   // seals buf^1 (B vmcnt + A lgkm) and releases buf
  }

  // ---- epilogue: 32-row passes through LDS, full-line coalesced stores ----
  float bb[4];
#pragma unroll
  for (int nt = 0; nt < 4; ++nt) bb[nt] = bias[wn + nt * 16 + lrow];
  float* ctile = (float*)smem;               // 32 x 260 floats = 33.3 KB
#pragma unroll
  for (int h = 0; h < TM / 32; ++h) {
    __syncthreads();
#pragma unroll
    for (int m2 = 0; m2 < 2; ++m2) {
      const int mt = h * 2 + m2;
      const int lr0 = m2 * 16 + lgrp * 4;
#pragma unroll
      for (int nt = 0; nt < 4; ++nt) {
        const int col = wn + nt * 16 + lrow;
#pragma unroll
        for (int j = 0; j < 4; ++j)
          ctile[(lr0 + j) * 260 + col] = acc[mt][nt][j] + bb[nt];
      }
    }
    __syncthreads();
#pragma unroll
    for (int i = 0; i < 8; ++i) {
      const int idx = i * 256 + tid, r = idx >> 6, c4 = (idx & 63) << 2;
      *(float4*)&C[(size_t)(brow + h * 32 + r) * 256 + c4] = *(const float4*)&ctile[r * 260 + c4];
    }
  }
}

// ---------------------------------------------------------------------------
// Weight prep: W fp32 [256][256] -> Bprep (pre-swizzled, K-step-tiled).
// Chunk t (16384 ushorts) is the exact LDS image for K-step t: row r holds
// [hi granules 0-3 | lo granules 4-7] of W[32t..32t+32][r], granule-XOR-
// swizzled by (r&7). global_load_lds copies it linearly; reads un-swizzle.
// ---------------------------------------------------------------------------
__global__ __launch_bounds__(256) void prep_wt(
    const float* __restrict__ W, ushort* __restrict__ Bprep)
{
  const int pg = blockIdx.x * 256 + threadIdx.x;  // 0..131071
  const int t = pg >> 14;
  const int p = pg & 16383;
  const int r = p >> 6;
  const int q = p & 63;
  const int g0 = (q >> 3) ^ (r & 7);              // unswizzled granule
  const int q0 = g0 * 8 + (q & 7);                // unswizzled ushort in row
  const int kk = q0 & 31;
  const float w = W[(size_t)(t * 32 + kk) * 256 + r];
  const ushort hi = f2bf_rn(w);
  Bprep[pg] = (q0 < 32) ? hi : f2bf_rn(w - bf2f(hi));
}

// ---------------------------------------------------------------------------
// Offsets + attention-logits projection (unchanged).
// ---------------------------------------------------------------------------
__global__ __launch_bounds__(128) void proj_kernel(
    const float* __restrict__ query,
    const float* __restrict__ W_off, const float* __restrict__ b_off,
    const float* __restrict__ W_attn, const float* __restrict__ b_attn,
    float* __restrict__ offs, float* __restrict__ logits)
{
  __shared__ float q_lds[8][256];
  const int row0 = blockIdx.x * 8;
  const int tid  = threadIdx.x;

  for (int i = tid; i < 512; i += 128) {
    const int r  = i >> 6;
    const int c4 = (i & 63) << 2;
    *(float4*)&q_lds[r][c4] = *(const float4*)&query[(size_t)(row0 + r) * 256 + c4];
  }
  __syncthreads();
  if (tid >= 96) return;

  float acc[8] = {};
  if (tid < 64) {
    for (int k4 = 0; k4 < 256; k4 += 4) {
      const float w0 = W_off[(k4 + 0) * 64 + tid];
      const float w1 = W_off[(k4 + 1) * 64 + tid];
      const float w2 = W_off[(k4 + 2) * 64 + tid];
      const float w3 = W_off[(k4 + 3) * 64 + tid];
#pragma unroll
      for (int r = 0; r < 8; ++r) {
        float4 q4 = *(const float4*)&q_lds[r][k4];
        acc[r] += q4.x * w0 + q4.y * w1 + q4.z * w2 + q4.w * w3;
      }
    }
    const float bb = b_off[tid];
#pragma unroll
    for (int r = 0; r < 8; ++r)
      offs[(size_t)(row0 + r) * 64 + tid] = acc[r] + bb;
  } else {
    const int j = tid - 64;
    for (int k4 = 0; k4 < 256; k4 += 4) {
      const float w0 = W_attn[(k4 + 0) * 32 + j];
      const float w1 = W_attn[(k4 + 1) * 32 + j];
      const float w2 = W_attn[(k4 + 2) * 32 + j];
      const float w3 = W_attn[(k4 + 3) * 32 + j];
#pragma unroll
      for (int r = 0; r < 8; ++r) {
        float4 q4 = *(const float4*)&q_lds[r][k4];
        acc[r] += q4.x * w0 + q4.y * w1 + q4.z * w2 + q4.w * w3;
      }
    }
    const float bb = b_attn[j];
#pragma unroll
    for (int r = 0; r < 8; ++r)
      logits[(size_t)(row0 + r) * 32 + j] = acc[r] + bb;
  }
}

// ---------------------------------------------------------------------------
// Softmax + bilinear sampling, wave-per-query, float4 per lane (unchanged).
// ---------------------------------------------------------------------------
__global__ __launch_bounds__(256, 8) void sample_kernel(
    const float* __restrict__ refp,    // [BQ,2]
    const float* __restrict__ offs,    // [BQ,64]  (h*8 + p*2 + c)
    const float* __restrict__ logits,  // [BQ,32]  (h*4 + p)
    const float* __restrict__ values,  // [B,HW,256]
    float* __restrict__ mid,           // [BQ,256]
    const int* __restrict__ hptr, const int* __restrict__ wptr,
    int Q, int HW)
{
  const int lane = threadIdx.x & 63;
  const int bq   = blockIdx.x * 4 + (threadIdx.x >> 6);
  const int b    = bq / Q;
  const int W_   = *wptr;
  const int H_   = *hptr;
  const int h    = lane >> 3;

  const float l0 = logits[(size_t)bq * 32 + h * 4 + 0];
  const float l1 = logits[(size_t)bq * 32 + h * 4 + 1];
  const float l2 = logits[(size_t)bq * 32 + h * 4 + 2];
  const float l3 = logits[(size_t)bq * 32 + h * 4 + 3];
  const float m  = fmaxf(fmaxf(l0, l1), fmaxf(l2, l3));
  const float e0 = __expf(l0 - m), e1 = __expf(l1 - m);
  const float e2 = __expf(l2 - m), e3 = __expf(l3 - m);
  const float inv = 1.0f / (e0 + e1 + e2 + e3);
  float wt[4] = {e0 * inv, e1 * inv, e2 * inv, e3 * inv};

  const float rx = refp[(size_t)bq * 2 + 0];
  const float ry = refp[(size_t)bq * 2 + 1];
  const float* vb = values + (size_t)b * HW * 256;
  const int ch = lane * 4;

  f32x4 acc = {0.f, 0.f, 0.f, 0.f};
#pragma unroll
  for (int p = 0; p < NPOINTS; ++p) {
    float lx = rx + offs[(size_t)bq * 64 + h * 8 + p * 2 + 0];
    float ly = ry + offs[(size_t)bq * 64 + h * 8 + p * 2 + 1];
    lx = fminf(fmaxf(lx, 0.0f), 1.0f);
    ly = fminf(fmaxf(ly, 0.0f), 1.0f);
    const float sx = lx * (float)(W_ - 1);
    const float sy = ly * (float)(H_ - 1);
    int x0 = (int)floorf(sx);
    int y0 = (int)floorf(sy);
    x0 = min(max(x0, 0), W_ - 1);
    y0 = min(max(y0, 0), H_ - 1);
    const int x1 = min(x0 + 1, W_ - 1);
    const int y1 = min(y0 + 1, H_ - 1);
    const float wx1 = sx - (float)x0, wx0 = 1.0f - wx1;
    const float wy1 = sy - (float)y0, wy0 = 1.0f - wy1;

    const f32x4 g00 = *(const f32x4*)&vb[(size_t)(y0 * W_ + x0) * 256 + ch];
    const f32x4 g10 = *(const f32x4*)&vb[(size_t)(y0 * W_ + x1) * 256 + ch];
    const f32x4 g01 = *(const f32x4*)&vb[(size_t)(y1 * W_ + x0) * 256 + ch];
    const f32x4 g11 = *(const f32x4*)&vb[(size_t)(y1 * W_ + x1) * 256 + ch];

    const float w00 = wx0 * wy0, w10 = wx1 * wy0, w01 = wx0 * wy1, w11 = wx1 * wy1;
    const float wp = wt[p];
#pragma unroll
    for (int j = 0; j < 4; ++j)
      acc[j] += wp * (g00[j] * w00 + g01[j] * w01 + g10[j] * w10 + g11[j] * w11);
  }
  *(f32x4*)&mid[(size_t)bq * 256 + ch] = acc;
}

// ---------------------------------------------------------------------------
extern "C" void kernel_launch(void* const* d_in, const int* in_sizes, int n_in,
                              void* d_out, int out_size, void* d_ws, size_t ws_size,
                              hipStream_t stream)
{
  const float* query   = (const float*)d_in[0];
  const float* refp    = (const float*)d_in[1];
  const float* input_f = (const float*)d_in[2];
  const int*   hptr    = (const int*)d_in[3];
  const int*   wptr    = (const int*)d_in[4];
  const float* W_off   = (const float*)d_in[5];
  const float* b_off   = (const float*)d_in[6];
  const float* W_attn  = (const float*)d_in[7];
  const float* b_attn  = (const float*)d_in[8];
  const float* W_val   = (const float*)d_in[9];
  const float* b_val   = (const float*)d_in[10];
  const float* W_out   = (const float*)d_in[11];
  const float* b_out   = (const float*)d_in[12];
  float* out = (float*)d_out;

  const int D   = 256;
  const int BQ  = in_sizes[0] / D;   // 16384
  const int B   = 8;
  const int Q   = BQ / B;            // 2048
  const int BHW = in_sizes[2] / D;   // 80000
  const int HW  = BHW / B;           // 10000

  char* ws = (char*)d_ws;
  float* values = (float*)ws;                                   // 81.92 MB
  size_t o = (size_t)BHW * D * sizeof(float);
  float* offsb  = (float*)(ws + o);  o += (size_t)BQ * 64 * sizeof(float);  // 4.19 MB
  float* logitb = (float*)(ws + o);  o += (size_t)BQ * 32 * sizeof(float);  // 2.10 MB
  float* mid    = (float*)(ws + o);                             // 16.78 MB

  // Pre-swizzled weight overlays on dead regions (256 KB each):
  //  - Bprep_val at head of `mid` (dead until sample writes mid)
  //  - Bprep_out at head of `offsb` (offs dead after sample)
  ushort* Bprep_val = (ushort*)mid;
  ushort* Bprep_out = (ushort*)offsb;

  // 1. values = input_flatten @ W_val + b_val
  prep_wt<<<512, 256, 0, stream>>>(W_val, Bprep_val);
  gemm_split3_n256<64><<<BHW / 64, 256, 0, stream>>>(
      input_f, Bprep_val, b_val, values, BHW, D);

  // 2. offsets + attention logits
  proj_kernel<<<BQ / 8, 128, 0, stream>>>(
      query, W_off, b_off, W_attn, b_attn, offsb, logitb);

  // 3. softmax + bilinear sampling -> mid
  sample_kernel<<<BQ / 4, 256, 0, stream>>>(
      refp, offsb, logitb, values, mid, hptr, wptr, Q, HW);

  // 4. out = mid @ W_out + b_out
  prep_wt<<<512, 256, 0, stream>>>(W_out, Bprep_out);
  gemm_split3_n256<32><<<BQ / 32, 256, 0, stream>>>(
      mid, Bprep_out, b_out, out, BQ, D);
}